// Round 10
// baseline (185.629 us; speedup 1.0000x reference)
//
#include <hip/hip_runtime.h>

typedef _Float16 half8 __attribute__((ext_vector_type(8)));
typedef _Float16 half4 __attribute__((ext_vector_type(4)));
typedef float f32x4 __attribute__((ext_vector_type(4)));

#define T_STEPS 256
#define NB      16
#define NBLOCKS (4096/NB)    // 256 blocks = 1 per CU
#define LOG2E   1.4426950408889634f

// merged activation buffer stride (f16 units): cols 0..63 = h1, 64..127 = h2.
// 136 = 8*17: b128 reads spread over the 8 bank-groups ((ln+lb)%8 permutation).
#define SH 136

__device__ __forceinline__ half8 cvt8s(const float* __restrict__ p, float s) {
    half8 r;
    #pragma unroll
    for (int j = 0; j < 8; ++j) r[j] = (_Float16)(p[j] * s);
    return r;
}

// LDS-only barrier: does NOT drain vmcnt, so global x prefetch stays in flight.
__device__ __forceinline__ void sync_lds() {
    asm volatile("s_waitcnt lgkmcnt(0)" ::: "memory");
    __builtin_amdgcn_s_barrier();
}

// Pipeline (one barrier per interval j, buffers alternate P = j&1):
//   L1 at j: h1(j)   = f(x(j), h1(j-1))       reads Hb[P].h1, writes Hb[1-P].h1
//   L2 at j: h2(j-2) = f(h1(j-2), h2(j-3))    h1(j-2) PRE-READ during interval
//            j-1 (published at barrier j-1 -> legal), h2(j-3) read post-barrier
//            covered by the 8 reg-ready h1-MFMAs. 258 intervals total.
__global__ __launch_bounds__(512, 1)
void lstm_v10(const float* __restrict__ x,
              const float* __restrict__ Wih0, const float* __restrict__ Whh0,
              const float* __restrict__ bih0, const float* __restrict__ bhh0,
              const float* __restrict__ Wih1, const float* __restrict__ Whh1,
              const float* __restrict__ bih1, const float* __restrict__ bhh1,
              const float* __restrict__ Wout, const float* __restrict__ bout,
              float* __restrict__ out)
{
    __shared__ _Float16 Hb[2][16][SH];

    const int tid  = threadIdx.x;
    const int w    = tid >> 6;
    const bool isL1 = (w < 4);          // waves 0-3: layer 1; waves 4-7: layer 2
    const int wq   = w & 3;
    const int l    = tid & 63;
    const int ln   = l & 15;            // weight row (A) / batch col (B)
    const int lb   = l >> 4;            // k sub-block / C-row group
    const int ub   = 16 * wq + 4 * lb;  // first unit this lane's acc covers
    const int gb0  = blockIdx.x * NB;

    // ---- weight A-fragments, register-resident, sign/scale pre-folded ----
    // gate q scale: i,f,o -> -log2e (exp2(acc) = e^{-raw}); g -> +2*log2e.
    // L1: wa[q][0] = x-slice (K 0..31), wa[q][1..2] = h1-slices; [3] unused.
    // L2: wa[q][0..3] = [h1 | h2] K-slices.
    half8 wa[4][4];
    f32x4 bv[4];
    if (isL1) {
        #pragma unroll
        for (int q = 0; q < 4; ++q) {
            const float s = (q == 2) ? 2.f * LOG2E : -LOG2E;
            const int g = 64 * q + 16 * wq + ln;
            wa[q][0] = cvt8s(Wih0 + g * 32 + 8 * lb, s);
            #pragma unroll
            for (int ks = 0; ks < 2; ++ks)
                wa[q][1 + ks] = cvt8s(Whh0 + g * 64 + 32 * ks + 8 * lb, s);
            #pragma unroll
            for (int jj = 0; jj < 4; ++jj) {
                const int gj = 64 * q + ub + jj;
                bv[q][jj] = (bih0[gj] + bhh0[gj]) * s;
            }
        }
    } else {
        #pragma unroll
        for (int q = 0; q < 4; ++q) {
            const float s = (q == 2) ? 2.f * LOG2E : -LOG2E;
            const int g = 64 * q + 16 * wq + ln;
            #pragma unroll
            for (int ks = 0; ks < 4; ++ks) {
                const int c0 = 32 * ks + 8 * lb;
                const float* p = (c0 < 64) ? (Wih1 + g * 64 + c0)
                                           : (Whh1 + g * 64 + (c0 - 64));
                wa[q][ks] = cvt8s(p, s);
            }
            #pragma unroll
            for (int jj = 0; jj < 4; ++jj) {
                const int gj = 64 * q + ub + jj;
                bv[q][jj] = (bih1[gj] + bhh1[gj]) * s;
            }
        }
    }

    float cst[4] = {0.f, 0.f, 0.f, 0.f};

    // ---- zero LDS (h1(-1)=0, h2(-1)=0) ----
    {
        unsigned int* z = (unsigned int*)Hb;
        for (int i = tid; i < (int)(sizeof(Hb) / 4); i += 512) z[i] = 0u;
    }

    // ---- L1 x path: lane owns x[batch gb0+ln][t][8lb..8lb+7]; 3-deep prefetch ----
    const float* xb = x + (long)(gb0 + ln) * T_STEPS * 32 + 8 * lb;
    f32x4 xr0 = {0.f,0.f,0.f,0.f}, xr1 = {0.f,0.f,0.f,0.f};
    f32x4 xq0 = {0.f,0.f,0.f,0.f}, xq1 = {0.f,0.f,0.f,0.f};
    f32x4 gxA[4], gxB[4];
    if (isL1) {
        // gx(0) = bias + W_x @ x(0)
        const f32x4 x0a = *(const f32x4*)(xb);
        const f32x4 x0b = *(const f32x4*)(xb + 4);
        half8 xf;
        #pragma unroll
        for (int j = 0; j < 4; ++j) { xf[j] = (_Float16)x0a[j]; xf[4+j] = (_Float16)x0b[j]; }
        #pragma unroll
        for (int q = 0; q < 4; ++q)
            gxA[q] = __builtin_amdgcn_mfma_f32_16x16x32_f16(wa[q][0], xf, bv[q], 0, 0, 0);
        xr0 = *(const f32x4*)(xb + 32);      // x(1)
        xr1 = *(const f32x4*)(xb + 36);
        xq0 = *(const f32x4*)(xb + 64);      // x(2)
        xq1 = *(const f32x4*)(xb + 68);
    }
    half8 pf0 = {}, pf1 = {};                // L2's pre-read h1 fragments
    sync_lds();

// LSTM cell update, weights pre-scaled: ei=e^{-i}, ef=e^{-f}, Eg=e^{2g}, eo=e^{-o}
// c' = [c*(1+ei)(1+Eg) + (Eg-1)(1+ef)] / ((1+ei)(1+Eg)(1+ef))
// h  = (Ec-1) / ((1+eo)(1+Ec)),  Ec = e^{2c'}
#define ACT1(A, JJ)                                                            \
    {                                                                          \
        const float ei = __builtin_amdgcn_exp2f(A[0][JJ]);                     \
        const float ef = __builtin_amdgcn_exp2f(A[1][JJ]);                     \
        const float Eg = __builtin_amdgcn_exp2f(A[2][JJ]);                     \
        const float eo = __builtin_amdgcn_exp2f(A[3][JJ]);                     \
        const float ti = 1.f + ei, tf = 1.f + ef, tg = 1.f + Eg;               \
        const float pig = ti * tg;                                             \
        const float num = fmaf(Eg - 1.f, tf, cst[JJ] * pig);                   \
        const float c   = num * __builtin_amdgcn_rcpf(pig * tf);               \
        cst[JJ] = c;                                                           \
        const float Ec  = __builtin_amdgcn_exp2f(fminf((2.f * LOG2E) * c, 120.f)); \
        hh[JJ] = (_Float16)((Ec - 1.f) *                                       \
                 __builtin_amdgcn_rcpf((1.f + eo) * (1.f + Ec)));              \
    }

#define STEP(J, P, GXC, GXN)                                                   \
    do {                                                                       \
        if (isL1 && (J) < T_STEPS) {                                           \
            /* issue h1(J-1) reads first */                                    \
            const half8 bf0 = *(const half8*)&Hb[P][ln][8 * lb];               \
            const half8 bf1 = *(const half8*)&Hb[P][ln][32 + 8 * lb];          \
            /* cover ds latency: build gx(J+1) from registers */               \
            half8 xf;                                                          \
            _Pragma("unroll")                                                  \
            for (int j = 0; j < 4; ++j) { xf[j] = (_Float16)xr0[j]; xf[4+j] = (_Float16)xr1[j]; } \
            _Pragma("unroll")                                                  \
            for (int q = 0; q < 4; ++q)                                        \
                GXN[q] = __builtin_amdgcn_mfma_f32_16x16x32_f16(wa[q][0], xf, bv[q], 0, 0, 0); \
            /* shift 3-deep x pipeline: load x(J+3) (~2 intervals ahead) */    \
            xr0 = xq0; xr1 = xq1;                                              \
            { const int jn = ((J) + 3 < T_STEPS) ? (J) + 3 : T_STEPS - 1;      \
              xq0 = *(const f32x4*)(xb + jn * 32);                             \
              xq1 = *(const f32x4*)(xb + jn * 32 + 4); }                       \
            /* recurrent part */                                               \
            _Pragma("unroll")                                                  \
            for (int q = 0; q < 4; ++q) {                                      \
                GXC[q] = __builtin_amdgcn_mfma_f32_16x16x32_f16(wa[q][1], bf0, GXC[q], 0, 0, 0); \
                GXC[q] = __builtin_amdgcn_mfma_f32_16x16x32_f16(wa[q][2], bf1, GXC[q], 0, 0, 0); \
            }                                                                  \
            half4 hh;                                                          \
            ACT1(GXC, 0) ACT1(GXC, 1) ACT1(GXC, 2) ACT1(GXC, 3)                \
            *(half4*)&Hb[1 - (P)][ln][ub] = hh;                                \
        }                                                                      \
        if (!isL1) {                                                           \
            if ((J) >= 2) {                                                    \
                /* h2(J-3) slices: only exposed reads, covered by h1-MFMAs */  \
                const half8 bf2 = *(const half8*)&Hb[P][ln][64 + 8 * lb];      \
                const half8 bf3 = *(const half8*)&Hb[P][ln][96 + 8 * lb];      \
                f32x4 acc[4];                                                  \
                _Pragma("unroll")                                              \
                for (int q = 0; q < 4; ++q) {                                  \
                    acc[q] = __builtin_amdgcn_mfma_f32_16x16x32_f16(wa[q][0], pf0, bv[q], 0, 0, 0); \
                    acc[q] = __builtin_amdgcn_mfma_f32_16x16x32_f16(wa[q][1], pf1, acc[q], 0, 0, 0); \
                }                                                              \
                _Pragma("unroll")                                              \
                for (int q = 0; q < 4; ++q) {                                  \
                    acc[q] = __builtin_amdgcn_mfma_f32_16x16x32_f16(wa[q][2], bf2, acc[q], 0, 0, 0); \
                    acc[q] = __builtin_amdgcn_mfma_f32_16x16x32_f16(wa[q][3], bf3, acc[q], 0, 0, 0); \
                }                                                              \
                /* pre-read h1(J-1) for next interval (latency under ACT) */   \
                pf0 = *(const half8*)&Hb[P][ln][8 * lb];                       \
                pf1 = *(const half8*)&Hb[P][ln][32 + 8 * lb];                  \
                half4 hh;                                                      \
                ACT1(acc, 0) ACT1(acc, 1) ACT1(acc, 2) ACT1(acc, 3)            \
                *(half4*)&Hb[1 - (P)][ln][64 + ub] = hh;                       \
            } else {                                                           \
                pf0 = *(const half8*)&Hb[P][ln][8 * lb];                       \
                pf1 = *(const half8*)&Hb[P][ln][32 + 8 * lb];                  \
            }                                                                  \
        }                                                                      \
        sync_lds();                                                            \
    } while (0)

    // 258 intervals: L1 active j<256, L2 (lag 2) active 2<=j<=257
    for (int jj = 0; jj < T_STEPS + 2; jj += 2) {
        STEP(jj, 0, gxA, gxB);
        STEP(jj + 1, 1, gxB, gxA);
    }

    // ---- output head: h2(255) written at interval 257 (P=1) -> Hb[0] ----
    if (tid < NB) {
        float s = bout[0];
        #pragma unroll
        for (int u8 = 0; u8 < 8; ++u8) {
            const half8 hv = *(const half8*)&Hb[0][tid][64 + 8 * u8];
            #pragma unroll
            for (int j = 0; j < 8; ++j)
                s += (float)hv[j] * Wout[8 * u8 + j];
        }
        out[gb0 + tid] = s;
    }
}

extern "C" void kernel_launch(void* const* d_in, const int* in_sizes, int n_in,
                              void* d_out, int out_size, void* d_ws, size_t ws_size,
                              hipStream_t stream) {
    const float* x    = (const float*)d_in[0];
    const float* Wih0 = (const float*)d_in[1];
    const float* Whh0 = (const float*)d_in[2];
    const float* bih0 = (const float*)d_in[3];
    const float* bhh0 = (const float*)d_in[4];
    const float* Wih1 = (const float*)d_in[5];
    const float* Whh1 = (const float*)d_in[6];
    const float* bih1 = (const float*)d_in[7];
    const float* bhh1 = (const float*)d_in[8];
    const float* Wout = (const float*)d_in[9];
    const float* bout = (const float*)d_in[10];

    hipLaunchKernelGGL(lstm_v10, dim3(NBLOCKS), dim3(512), 0, stream,
                       x, Wih0, Whh0, bih0, bhh0,
                       Wih1, Whh1, bih1, bhh1, Wout, bout,
                       (float*)d_out);
}

// Round 11
// 177.711 us; speedup vs baseline: 1.0446x; 1.0446x over previous
//
#include <hip/hip_runtime.h>

typedef _Float16 half8 __attribute__((ext_vector_type(8)));
typedef _Float16 half4 __attribute__((ext_vector_type(4)));
typedef float f32x4 __attribute__((ext_vector_type(4)));

#define T_STEPS 256
#define NB      16
#define NBLOCKS (4096/NB)    // 256 blocks = 1 per CU
#define LOG2E   1.4426950408889634f

// merged activation buffer stride (f16 units): cols 0..63 = h1, 64..127 = h2.
#define SH 136

__device__ __forceinline__ half8 cvt8s(const float* __restrict__ p, float s) {
    half8 r;
    #pragma unroll
    for (int j = 0; j < 8; ++j) r[j] = (_Float16)(p[j] * s);
    return r;
}

// LDS-only barrier: does NOT drain vmcnt, so global x prefetch stays in flight.
__device__ __forceinline__ void sync_lds() {
    asm volatile("s_waitcnt lgkmcnt(0)" ::: "memory");
    __builtin_amdgcn_s_barrier();
}

// Pipeline (one barrier per interval j, buffer parity P = j&1):
//   L1 at j: h1(j)   = f(x(j), h1(j-1))     reads Hb[P].h1, writes Hb[1-P].h1
//   L2 at j: h2(j-2) = f(h1(j-2), h2(j-3))  h1(j-2) comes from pf regs
//            (PRE-READ during interval j-1 from Hb[P'].h1, which was published
//            at the barrier ending j-2 and is stable through j-1);
//            h2(j-3) read post-barrier from Hb[P].h2, covered by the 8
//            register-ready pf-MFMAs. Pre-read for j+1 issues BEFORE ACT so
//            ACT's ~300cy covers its latency (no lgkmcnt skew at the barrier).
__global__ __launch_bounds__(512, 1)
void lstm_v11(const float* __restrict__ x,
              const float* __restrict__ Wih0, const float* __restrict__ Whh0,
              const float* __restrict__ bih0, const float* __restrict__ bhh0,
              const float* __restrict__ Wih1, const float* __restrict__ Whh1,
              const float* __restrict__ bih1, const float* __restrict__ bhh1,
              const float* __restrict__ Wout, const float* __restrict__ bout,
              float* __restrict__ out)
{
    __shared__ _Float16 Hb[2][16][SH];

    const int tid  = threadIdx.x;
    const int w    = tid >> 6;
    const bool isL1 = (w < 4);          // waves 0-3: layer 1; waves 4-7: layer 2
    const int wq   = w & 3;
    const int l    = tid & 63;
    const int ln   = l & 15;            // weight row (A) / batch col (B)
    const int lb   = l >> 4;            // k sub-block / C-row group
    const int ub   = 16 * wq + 4 * lb;  // first unit this lane's acc covers
    const int gb0  = blockIdx.x * NB;

    // ---- weight A-fragments, register-resident, sign/scale pre-folded ----
    // gate q scale: i,f,o -> -log2e (exp2(acc) = e^{-raw}); g -> +2*log2e.
    // L1: wa[q][0] = x-slice (K 0..31), wa[q][1..2] = h1-slices; [3] unused.
    // L2: wa[q][0..3] = [h1 | h2] K-slices.
    half8 wa[4][4];
    f32x4 bv[4];
    if (isL1) {
        #pragma unroll
        for (int q = 0; q < 4; ++q) {
            const float s = (q == 2) ? 2.f * LOG2E : -LOG2E;
            const int g = 64 * q + 16 * wq + ln;
            wa[q][0] = cvt8s(Wih0 + g * 32 + 8 * lb, s);
            #pragma unroll
            for (int ks = 0; ks < 2; ++ks)
                wa[q][1 + ks] = cvt8s(Whh0 + g * 64 + 32 * ks + 8 * lb, s);
            #pragma unroll
            for (int jj = 0; jj < 4; ++jj) {
                const int gj = 64 * q + ub + jj;
                bv[q][jj] = (bih0[gj] + bhh0[gj]) * s;
            }
        }
    } else {
        #pragma unroll
        for (int q = 0; q < 4; ++q) {
            const float s = (q == 2) ? 2.f * LOG2E : -LOG2E;
            const int g = 64 * q + 16 * wq + ln;
            #pragma unroll
            for (int ks = 0; ks < 4; ++ks) {
                const int c0 = 32 * ks + 8 * lb;
                const float* p = (c0 < 64) ? (Wih1 + g * 64 + c0)
                                           : (Whh1 + g * 64 + (c0 - 64));
                wa[q][ks] = cvt8s(p, s);
            }
            #pragma unroll
            for (int jj = 0; jj < 4; ++jj) {
                const int gj = 64 * q + ub + jj;
                bv[q][jj] = (bih1[gj] + bhh1[gj]) * s;
            }
        }
    }

    float cst[4] = {0.f, 0.f, 0.f, 0.f};

    // ---- zero LDS (h1(-1)=0, h2(-1)=h2(-2)=0) ----
    {
        unsigned int* z = (unsigned int*)Hb;
        for (int i = tid; i < (int)(sizeof(Hb) / 4); i += 512) z[i] = 0u;
    }

    // ---- L1 x path: lane owns x[batch gb0+ln][t][8lb..8lb+7]; 2-deep ----
    const float* xb = x + (long)(gb0 + ln) * T_STEPS * 32 + 8 * lb;
    f32x4 xr0 = {0.f,0.f,0.f,0.f}, xr1 = {0.f,0.f,0.f,0.f};
    f32x4 gxA[4], gxB[4];
    if (isL1) {
        // gx(0) = bias + W_x @ x(0)
        const f32x4 x0a = *(const f32x4*)(xb);
        const f32x4 x0b = *(const f32x4*)(xb + 4);
        half8 xf;
        #pragma unroll
        for (int j = 0; j < 4; ++j) { xf[j] = (_Float16)x0a[j]; xf[4+j] = (_Float16)x0b[j]; }
        #pragma unroll
        for (int q = 0; q < 4; ++q)
            gxA[q] = __builtin_amdgcn_mfma_f32_16x16x32_f16(wa[q][0], xf, bv[q], 0, 0, 0);
        xr0 = *(const f32x4*)(xb + 32);      // x(1)
        xr1 = *(const f32x4*)(xb + 36);
    }
    half8 pf0 = {}, pf1 = {};                // L2's pre-read h1 fragments
    sync_lds();

// LSTM cell update, weights pre-scaled: ei=e^{-i}, ef=e^{-f}, Eg=e^{2g}, eo=e^{-o}
// c' = [c*(1+ei)(1+Eg) + (Eg-1)(1+ef)] / ((1+ei)(1+Eg)(1+ef))
// h  = (Ec-1) / ((1+eo)(1+Ec)),  Ec = e^{2c'}
#define ACT1(A, JJ)                                                            \
    {                                                                          \
        const float ei = __builtin_amdgcn_exp2f(A[0][JJ]);                     \
        const float ef = __builtin_amdgcn_exp2f(A[1][JJ]);                     \
        const float Eg = __builtin_amdgcn_exp2f(A[2][JJ]);                     \
        const float eo = __builtin_amdgcn_exp2f(A[3][JJ]);                     \
        const float ti = 1.f + ei, tf = 1.f + ef, tg = 1.f + Eg;               \
        const float pig = ti * tg;                                             \
        const float num = fmaf(Eg - 1.f, tf, cst[JJ] * pig);                   \
        const float c   = num * __builtin_amdgcn_rcpf(pig * tf);               \
        cst[JJ] = c;                                                           \
        const float Ec  = __builtin_amdgcn_exp2f(fminf((2.f * LOG2E) * c, 120.f)); \
        hh[JJ] = (_Float16)((Ec - 1.f) *                                       \
                 __builtin_amdgcn_rcpf((1.f + eo) * (1.f + Ec)));              \
    }

#define STEP(J, P, GXC, GXN)                                                   \
    do {                                                                       \
        if (isL1 && (J) < T_STEPS) {                                           \
            /* issue h1(J-1) reads first */                                    \
            const half8 bf0 = *(const half8*)&Hb[P][ln][8 * lb];               \
            const half8 bf1 = *(const half8*)&Hb[P][ln][32 + 8 * lb];          \
            /* cover ds latency: build gx(J+1) from registers */               \
            half8 xf;                                                          \
            _Pragma("unroll")                                                  \
            for (int j = 0; j < 4; ++j) { xf[j] = (_Float16)xr0[j]; xf[4+j] = (_Float16)xr1[j]; } \
            _Pragma("unroll")                                                  \
            for (int q = 0; q < 4; ++q)                                        \
                GXN[q] = __builtin_amdgcn_mfma_f32_16x16x32_f16(wa[q][0], xf, bv[q], 0, 0, 0); \
            /* prefetch x(J+2); vmcnt never drained at barrier */              \
            { const int jn = ((J) + 2 < T_STEPS) ? (J) + 2 : T_STEPS - 1;      \
              xr0 = *(const f32x4*)(xb + jn * 32);                             \
              xr1 = *(const f32x4*)(xb + jn * 32 + 4); }                       \
            /* recurrent part */                                               \
            __builtin_amdgcn_s_setprio(1);                                     \
            _Pragma("unroll")                                                  \
            for (int q = 0; q < 4; ++q) {                                      \
                GXC[q] = __builtin_amdgcn_mfma_f32_16x16x32_f16(wa[q][1], bf0, GXC[q], 0, 0, 0); \
                GXC[q] = __builtin_amdgcn_mfma_f32_16x16x32_f16(wa[q][2], bf1, GXC[q], 0, 0, 0); \
            }                                                                  \
            __builtin_amdgcn_s_setprio(0);                                     \
            half4 hh;                                                          \
            ACT1(GXC, 0) ACT1(GXC, 1) ACT1(GXC, 2) ACT1(GXC, 3)                \
            *(half4*)&Hb[1 - (P)][ln][ub] = hh;                                \
        }                                                                      \
        if (!isL1) {                                                           \
            if ((J) >= 2) {                                                    \
                /* h2(J-3): only exposed reads, covered by 8 pf-MFMAs */       \
                const half8 bf2 = *(const half8*)&Hb[P][ln][64 + 8 * lb];      \
                const half8 bf3 = *(const half8*)&Hb[P][ln][96 + 8 * lb];      \
                f32x4 acc[4];                                                  \
                __builtin_amdgcn_s_setprio(1);                                 \
                _Pragma("unroll")                                              \
                for (int q = 0; q < 4; ++q) {                                  \
                    acc[q] = __builtin_amdgcn_mfma_f32_16x16x32_f16(wa[q][0], pf0, bv[q], 0, 0, 0); \
                    acc[q] = __builtin_amdgcn_mfma_f32_16x16x32_f16(wa[q][1], pf1, acc[q], 0, 0, 0); \
                }                                                              \
                _Pragma("unroll")                                              \
                for (int q = 0; q < 4; ++q) {                                  \
                    acc[q] = __builtin_amdgcn_mfma_f32_16x16x32_f16(wa[q][2], bf2, acc[q], 0, 0, 0); \
                    acc[q] = __builtin_amdgcn_mfma_f32_16x16x32_f16(wa[q][3], bf3, acc[q], 0, 0, 0); \
                }                                                              \
                __builtin_amdgcn_s_setprio(0);                                 \
                /* pre-read h1(J-1) for interval J+1; ACT covers latency */    \
                pf0 = *(const half8*)&Hb[P][ln][8 * lb];                       \
                pf1 = *(const half8*)&Hb[P][ln][32 + 8 * lb];                  \
                half4 hh;                                                      \
                ACT1(acc, 0) ACT1(acc, 1) ACT1(acc, 2) ACT1(acc, 3)            \
                *(half4*)&Hb[1 - (P)][ln][64 + ub] = hh;                       \
            } else {                                                           \
                pf0 = *(const half8*)&Hb[P][ln][8 * lb];                       \
                pf1 = *(const half8*)&Hb[P][ln][32 + 8 * lb];                  \
            }                                                                  \
        }                                                                      \
        sync_lds();                                                            \
    } while (0)

    // 258 intervals: L1 active j<256, L2 (lag 2) computes h2(j-2) for 2<=j<=257
    for (int jj = 0; jj < T_STEPS + 2; jj += 2) {
        STEP(jj, 0, gxA, gxB);
        STEP(jj + 1, 1, gxB, gxA);
    }

    // ---- output head: h2(255) computed at interval 257 (P=1) -> Hb[0] ----
    if (tid < NB) {
        float s = bout[0];
        #pragma unroll
        for (int u8 = 0; u8 < 8; ++u8) {
            const half8 hv = *(const half8*)&Hb[0][tid][64 + 8 * u8];
            #pragma unroll
            for (int j = 0; j < 8; ++j)
                s += (float)hv[j] * Wout[8 * u8 + j];
        }
        out[gb0 + tid] = s;
    }
}

extern "C" void kernel_launch(void* const* d_in, const int* in_sizes, int n_in,
                              void* d_out, int out_size, void* d_ws, size_t ws_size,
                              hipStream_t stream) {
    const float* x    = (const float*)d_in[0];
    const float* Wih0 = (const float*)d_in[1];
    const float* Whh0 = (const float*)d_in[2];
    const float* bih0 = (const float*)d_in[3];
    const float* bhh0 = (const float*)d_in[4];
    const float* Wih1 = (const float*)d_in[5];
    const float* Whh1 = (const float*)d_in[6];
    const float* bih1 = (const float*)d_in[7];
    const float* bhh1 = (const float*)d_in[8];
    const float* Wout = (const float*)d_in[9];
    const float* bout = (const float*)d_in[10];

    hipLaunchKernelGGL(lstm_v11, dim3(NBLOCKS), dim3(512), 0, stream,
                       x, Wih0, Whh0, bih0, bhh0,
                       Wih1, Whh1, bih1, bhh1, Wout, bout,
                       (float*)d_out);
}